// Round 6
// baseline (49.303 us; speedup 1.0000x reference)
//
#include <hip/hip_runtime.h>

// CompositionTransform  B=2, C=3, D=128, H=160, W=160, range_flow=0.4
// out[b,c,d,h,w] = trilerp_border(flow_2[b,c], (w,h,d)+rf*flow_1[b,:,d,h,w]) + flow_1[b,c,d,h,w]
//
// R5: double-buffered LDS staging (issue-early). R4's single slab serialized
//     each block twice on vmcnt(0)-drained DMA between channel phases. Now
//     channel c+1's global_load_lds DMA is issued BEFORE computing channel c,
//     into the other buffer; the __syncthreads() at phase end drains it after
//     ~2us of compute has hidden the HBM latency. Barriers 5 -> 3.
//     Slab geometry, clamped-border staging, outlier fallback: R4-verified.

constexpr int DD = 128, HH = 160, WW = 160;
constexpr int HW = HH * WW;              // 25600
constexpr int SP = DD * HW;              // 3276800
constexpr int TX = 32, TH = 8, TD = 8;   // output tile: 32x8x8, 8 outputs/thread (d)
constexpr int PX = 40, PY = 12, PZ = 12; // staged slab floats (x,y,z)
constexpr int PHF = PX * PY * PZ;        // 5760 floats = 22.5 KB
constexpr int VSLOT = PHF / 4;           // 1440 float4 slots
constexpr int VPAD = VSLOT + 32;         // +32-slot pad: masked-tail insurance
constexpr int NTX = WW / TX, NTH = HH / TH, NTD = DD / TD; // 5,20,16
constexpr int NB = 2 * NTX * NTH * NTD;  // 3200 blocks (mult of 8)

#define AS1 __attribute__((address_space(1)))
#define AS3 __attribute__((address_space(3)))

__global__ __launch_bounds__(256, 4) void comp_xform_db(
    const float* __restrict__ f1,
    const float* __restrict__ f2,
    const float* __restrict__ rfp,
    float* __restrict__ out)
{
    __shared__ __align__(16) float4 slab[2][VPAD];   // 47104 B -> 3 blocks/CU

    const int tid = threadIdx.x;

    // XCD-chunked bijective swizzle (NB % 8 == 0)
    const int bid = blockIdx.x;
    const int wg  = (bid & 7) * (NB / 8) + (bid >> 3);

    const int tx = wg % NTX; int r_ = wg / NTX;
    const int th = r_ % NTH; r_ /= NTH;
    const int td = r_ % NTD; const int b = r_ / NTD;

    const int x0 = tx * TX, h0 = th * TH, d0 = td * TD;
    const int xlo = x0 - 4, ylo = h0 - 2, zlo = d0 - 2;

    const size_t boff = (size_t)b * (size_t)(3 * SP);
    const float* __restrict__ f1b = f1 + boff;
    const float* __restrict__ f2b = f2 + boff;
    float* __restrict__ ob = out + boff;

    const float rf = rfp[0];

    const int wl = tid & 31, hh = tid >> 5;
    const int w = x0 + wl, h = h0 + hh;
    const int sp0 = (d0 * HH + h) * WW + w;
    const int wbase = tid & 192;             // wave-uniform float4-slot base

    // ---- staging source offsets (same for all 3 channels) ----
    int goff[6];
#pragma unroll
    for (int r = 0; r < 6; ++r) {
        const int s = r * 256 + tid;
        const int row = s / 10, k = s - row * 10;      // 10 float4-runs per row
        const int rz = row / PY, ry = row - rz * PY;
        const int gz = min(max(zlo + rz, 0), DD - 1);
        const int gy = min(max(ylo + ry, 0), HH - 1);
        const int gx = min(max(xlo + 4 * k, 0), WW - 4);
        goff[r] = (s < VSLOT) ? ((gz * HH + gy) * WW + gx) : -1;
    }

    // DMA stage: channel src -> slab[buf] (wave-uniform LDS base + lane*16)
    auto stage = [&](int buf, const float* __restrict__ src) {
#pragma unroll
        for (int r = 0; r < 6; ++r) {
            if (goff[r] >= 0) {
                const float* gp = src + goff[r];
                AS3 void* lp = (AS3 void*)&slab[buf][r * 256 + wbase];
                __builtin_amdgcn_global_load_lds((const AS1 void*)gp, lp, 16, 0, 0);
            }
        }
    };

    // ---- stage channel 0 into buf0 immediately ----
    stage(0, f2b);

    // ---- flow_1: issue all 24 loads (overlaps the DMA) ----
    float f1s0[8], f1s1[8], f1s2[8];
#pragma unroll
    for (int dd = 0; dd < TD; ++dd) {
        const int sp = sp0 + dd * HW;
        f1s0[dd] = f1b[sp];
        f1s1[dd] = f1b[SP + sp];
        f1s2[dd] = f1b[2 * SP + sp];
    }

    // ---- positions, slab offsets, weights; ok-mask for outliers ----
    int voff[8]; float wxs[8], wys[8], wzs[8]; unsigned okm = 0;
#pragma unroll
    for (int dd = 0; dd < TD; ++dd) {
        const float x = fminf(fmaxf((float)w + rf * f1s0[dd], 0.f), (float)(WW - 1));
        const float y = fminf(fmaxf((float)h + rf * f1s1[dd], 0.f), (float)(HH - 1));
        const float z = fminf(fmaxf((float)(d0 + dd) + rf * f1s2[dd], 0.f), (float)(DD - 1));
        const float fx = floorf(x), fy = floorf(y), fz = floorf(z);
        const int rx = (int)fx - xlo, ry = (int)fy - ylo, rz = (int)fz - zlo;
        const bool ok = ((unsigned)rx <= 38u) & ((unsigned)ry <= 10u) & ((unsigned)rz <= 10u);
        okm |= (ok ? 1u : 0u) << dd;
        voff[dd] = ok ? ((rz * PY + ry) * PX + rx) : 0;
        wxs[dd] = ok ? (x - fx) : x;     // fallback lanes stash raw coords
        wys[dd] = ok ? (y - fy) : y;
        wzs[dd] = ok ? (z - fz) : z;
    }

    __syncthreads();   // vmcnt(0) + barrier: buf0 (ch0) ready

#pragma unroll
    for (int c = 0; c < 3; ++c) {
        // issue next channel's DMA into the other buffer BEFORE compute:
        // its HBM latency hides under this phase's LDS/VALU work.
        if (c < 2) stage((c + 1) & 1, f2b + (size_t)(c + 1) * SP);

        const float* __restrict__ br  = (const float*)slab[c & 1];
        const float* __restrict__ f2c = f2b + (size_t)c * SP;   // fallback source
        float* __restrict__ oc = ob + (size_t)c * SP;

#pragma unroll
        for (int dd = 0; dd < TD; ++dd) {
            const float* p = br + voff[dd];
            const float wx = wxs[dd], wy = wys[dd], wz = wzs[dd];
            const float ax = 1.f - wx, ay = 1.f - wy, az = 1.f - wz;
            const float a0 = p[0],            a1 = p[1];
            const float b0 = p[PX],           b1 = p[PX + 1];
            const float c0 = p[PX * PY],      c1 = p[PX * PY + 1];
            const float e0 = p[PX * PY + PX], e1 = p[PX * PY + PX + 1];
            const float top = ay * fmaf(a0, ax, a1 * wx) + wy * fmaf(b0, ax, b1 * wx);
            const float bot = ay * fmaf(c0, ax, c1 * wx) + wy * fmaf(e0, ax, e1 * wx);
            const float res = az * top + wz * bot;
            const float f1c = (c == 0) ? f1s0[dd] : ((c == 1) ? f1s1[dd] : f1s2[dd]);
            oc[sp0 + dd * HW] = res + f1c;
        }

        // rare exact fallback (|displacement|>2); whole wave skips via exec-z
        if (okm != 255u) {
#pragma unroll
            for (int dd = 0; dd < TD; ++dd) {
                if (!((okm >> dd) & 1u)) {
                    const float X = wxs[dd], Y = wys[dd], Z = wzs[dd];
                    const float fx = floorf(X), fy = floorf(Y), fz = floorf(Z);
                    const float wx = X - fx, wy = Y - fy, wz = Z - fz;
                    const int ix0 = (int)fx, iy0 = (int)fy, iz0 = (int)fz;
                    const int ix1 = min(ix0 + 1, WW - 1);
                    const int iy1 = min(iy0 + 1, HH - 1);
                    const int iz1 = min(iz0 + 1, DD - 1);
                    const int q00 = (iz0 * HH + iy0) * WW, q01 = (iz0 * HH + iy1) * WW;
                    const int q10 = (iz1 * HH + iy0) * WW, q11 = (iz1 * HH + iy1) * WW;
                    const float c000 = f2c[q00 + ix0], c001 = f2c[q00 + ix1];
                    const float c010 = f2c[q01 + ix0], c011 = f2c[q01 + ix1];
                    const float c100 = f2c[q10 + ix0], c101 = f2c[q10 + ix1];
                    const float c110 = f2c[q11 + ix0], c111 = f2c[q11 + ix1];
                    const float ax = 1.f - wx, ay = 1.f - wy, az = 1.f - wz;
                    const float top = ay * (c000 * ax + c001 * wx) + wy * (c010 * ax + c011 * wx);
                    const float bot = ay * (c100 * ax + c101 * wx) + wy * (c110 * ax + c111 * wx);
                    const float f1c = (c == 0) ? f1s0[dd] : ((c == 1) ? f1s1[dd] : f1s2[dd]);
                    oc[sp0 + dd * HW] = az * top + wz * bot + f1c;
                }
            }
        }

        // phase end: all waves done reading slab[c&1]; drains next DMA too
        if (c < 2) __syncthreads();
    }
}

extern "C" void kernel_launch(void* const* d_in, const int* in_sizes, int n_in,
                              void* d_out, int out_size, void* d_ws, size_t ws_size,
                              hipStream_t stream) {
    const float* f1  = (const float*)d_in[0];
    const float* f2  = (const float*)d_in[1];
    // d_in[2] = sample_grid (identity meshgrid) — unused by construction
    const float* rfp = (const float*)d_in[3];
    float* out = (float*)d_out;

    comp_xform_db<<<NB, 256, 0, stream>>>(f1, f2, rfp, out);
}

// Round 7
// 45.623 us; speedup vs baseline: 1.0807x; 1.0807x over previous
//
#include <hip/hip_runtime.h>

// CompositionTransform  B=2, C=3, D=128, H=160, W=160, range_flow=0.4
// out[b,c,d,h,w] = trilerp_border(flow_2[b,c], (w,h,d)+rf*flow_1[b,:,d,h,w]) + flow_1[b,c,d,h,w]
//
// R6: kill the LDS read bank conflicts. R3/R4/R5 all show the same 8.27M
//     SQ_LDS_BANK_CONFLICT from the jittered corner reads: with PX=40 the
//     bank index is (rx + 8*jy) mod 32 -- per-lane y-jitter scatters banks.
//     PX=64 makes row stride == 0 mod 32: bank = rx only; y/z jitter is gone
//     from the bank index. Slab 64x12x12 = 36KB -> 4 blocks/CU (occ 50%),
//     2304 float4 slots = 9*256 -> branch-free staging, no ragged tail.
//     Structure is R4's (single slab, 3 channel phases): R5's double-buffer
//     was neutral-negative (occupancy), so reverted.

constexpr int DD = 128, HH = 160, WW = 160;
constexpr int HW = HH * WW;              // 25600
constexpr int SP = DD * HW;              // 3276800
constexpr int TX = 32, TH = 8, TD = 8;   // output tile: 32x8x8, 8 outputs/thread (d)
constexpr int PX = 64, PY = 12, PZ = 12; // staged slab floats; PX%32==0 -> clean banks
constexpr int PHF = PX * PY * PZ;        // 9216 floats = 36 KB
constexpr int VSLOT = PHF / 4;           // 2304 float4 slots = 9 * 256
constexpr int RUNS = VSLOT / 256;        // 9 staging runs/thread, exact
constexpr int NTX = WW / TX, NTH = HH / TH, NTD = DD / TD; // 5,20,16
constexpr int NB = 2 * NTX * NTH * NTD;  // 3200 blocks (mult of 8)

#define AS1 __attribute__((address_space(1)))
#define AS3 __attribute__((address_space(3)))

__global__ __launch_bounds__(256, 4) void comp_xform_px64(
    const float* __restrict__ f1,
    const float* __restrict__ f2,
    const float* __restrict__ rfp,
    float* __restrict__ out)
{
    __shared__ __align__(16) float slab[PHF];   // 36864 B -> 4 blocks/CU

    const int tid = threadIdx.x;

    // XCD-chunked bijective swizzle (NB % 8 == 0)
    const int bid = blockIdx.x;
    const int wg  = (bid & 7) * (NB / 8) + (bid >> 3);

    const int tx = wg % NTX; int r_ = wg / NTX;
    const int th = r_ % NTH; r_ /= NTH;
    const int td = r_ % NTD; const int b = r_ / NTD;

    const int x0 = tx * TX, h0 = th * TH, d0 = td * TD;
    const int xlo = x0 - 4, ylo = h0 - 2, zlo = d0 - 2;

    const size_t boff = (size_t)b * (size_t)(3 * SP);
    const float* __restrict__ f1b = f1 + boff;
    const float* __restrict__ f2b = f2 + boff;
    float* __restrict__ ob = out + boff;

    const float rf = rfp[0];

    const int wl = tid & 31, hh = tid >> 5;
    const int w = x0 + wl, h = h0 + hh;
    const int sp0 = (d0 * HH + h) * WW + w;
    const int wbase = tid & 192;             // wave-uniform float4-slot base

    // ---- staging source offsets (same for all 3 channels), 16 runs/row ----
    int goff[RUNS];
#pragma unroll
    for (int r = 0; r < RUNS; ++r) {
        const int s = r * 256 + tid;
        const int row = s >> 4, k = s & 15;            // 16 float4-runs per row
        const int rz = row / PY, ry = row - rz * PY;
        const int gz = min(max(zlo + rz, 0), DD - 1);
        const int gy = min(max(ylo + ry, 0), HH - 1);
        const int gx = min(max(xlo + 4 * k, 0), WW - 4);
        goff[r] = (gz * HH + gy) * WW + gx;
    }

    // DMA stage: channel src -> slab (wave-uniform LDS base + lane*16)
    auto stage = [&](const float* __restrict__ src) {
#pragma unroll
        for (int r = 0; r < RUNS; ++r) {
            const float* gp = src + goff[r];
            AS3 void* lp = (AS3 void*)&slab[(r * 256 + wbase) * 4];
            __builtin_amdgcn_global_load_lds((const AS1 void*)gp, lp, 16, 0, 0);
        }
    };

    // ---- stage channel 0 immediately ----
    stage(f2b);

    // ---- flow_1: issue all 24 loads (overlaps the DMA) ----
    float f1s0[8], f1s1[8], f1s2[8];
#pragma unroll
    for (int dd = 0; dd < TD; ++dd) {
        const int sp = sp0 + dd * HW;
        f1s0[dd] = f1b[sp];
        f1s1[dd] = f1b[SP + sp];
        f1s2[dd] = f1b[2 * SP + sp];
    }

    // ---- positions, slab offsets, weights; ok-mask for outliers ----
    int voff[8]; float wxs[8], wys[8], wzs[8]; unsigned okm = 0;
#pragma unroll
    for (int dd = 0; dd < TD; ++dd) {
        const float x = fminf(fmaxf((float)w + rf * f1s0[dd], 0.f), (float)(WW - 1));
        const float y = fminf(fmaxf((float)h + rf * f1s1[dd], 0.f), (float)(HH - 1));
        const float z = fminf(fmaxf((float)(d0 + dd) + rf * f1s2[dd], 0.f), (float)(DD - 1));
        const float fx = floorf(x), fy = floorf(y), fz = floorf(z);
        const int rx = (int)fx - xlo, ry = (int)fy - ylo, rz = (int)fz - zlo;
        const bool ok = ((unsigned)rx <= 38u) & ((unsigned)ry <= 10u) & ((unsigned)rz <= 10u);
        okm |= (ok ? 1u : 0u) << dd;
        voff[dd] = ok ? ((rz * PY + ry) * PX + rx) : 0;
        wxs[dd] = ok ? (x - fx) : x;     // fallback lanes stash raw coords
        wys[dd] = ok ? (y - fy) : y;
        wzs[dd] = ok ? (z - fz) : z;
    }

    __syncthreads();   // vmcnt(0) + barrier: slab (ch0) ready

#pragma unroll
    for (int c = 0; c < 3; ++c) {
        const float* __restrict__ br  = slab;
        const float* __restrict__ f2c = f2b + (size_t)c * SP;   // fallback source
        float* __restrict__ oc = ob + (size_t)c * SP;

#pragma unroll
        for (int dd = 0; dd < TD; ++dd) {
            const float* p = br + voff[dd];
            const float wx = wxs[dd], wy = wys[dd], wz = wzs[dd];
            const float ax = 1.f - wx, ay = 1.f - wy, az = 1.f - wz;
            const float a0 = p[0],            a1 = p[1];
            const float b0 = p[PX],           b1 = p[PX + 1];
            const float c0 = p[PX * PY],      c1 = p[PX * PY + 1];
            const float e0 = p[PX * PY + PX], e1 = p[PX * PY + PX + 1];
            const float top = ay * fmaf(a0, ax, a1 * wx) + wy * fmaf(b0, ax, b1 * wx);
            const float bot = ay * fmaf(c0, ax, c1 * wx) + wy * fmaf(e0, ax, e1 * wx);
            const float res = az * top + wz * bot;
            const float f1c = (c == 0) ? f1s0[dd] : ((c == 1) ? f1s1[dd] : f1s2[dd]);
            oc[sp0 + dd * HW] = res + f1c;
        }

        // rare exact fallback (|displacement|>2); whole wave skips via exec-z
        if (okm != 255u) {
#pragma unroll
            for (int dd = 0; dd < TD; ++dd) {
                if (!((okm >> dd) & 1u)) {
                    const float X = wxs[dd], Y = wys[dd], Z = wzs[dd];
                    const float fx = floorf(X), fy = floorf(Y), fz = floorf(Z);
                    const float wx = X - fx, wy = Y - fy, wz = Z - fz;
                    const int ix0 = (int)fx, iy0 = (int)fy, iz0 = (int)fz;
                    const int ix1 = min(ix0 + 1, WW - 1);
                    const int iy1 = min(iy0 + 1, HH - 1);
                    const int iz1 = min(iz0 + 1, DD - 1);
                    const int q00 = (iz0 * HH + iy0) * WW, q01 = (iz0 * HH + iy1) * WW;
                    const int q10 = (iz1 * HH + iy0) * WW, q11 = (iz1 * HH + iy1) * WW;
                    const float c000 = f2c[q00 + ix0], c001 = f2c[q00 + ix1];
                    const float c010 = f2c[q01 + ix0], c011 = f2c[q01 + ix1];
                    const float c100 = f2c[q10 + ix0], c101 = f2c[q10 + ix1];
                    const float c110 = f2c[q11 + ix0], c111 = f2c[q11 + ix1];
                    const float ax = 1.f - wx, ay = 1.f - wy, az = 1.f - wz;
                    const float top = ay * (c000 * ax + c001 * wx) + wy * (c010 * ax + c011 * wx);
                    const float bot = ay * (c100 * ax + c101 * wx) + wy * (c110 * ax + c111 * wx);
                    const float f1c = (c == 0) ? f1s0[dd] : ((c == 1) ? f1s1[dd] : f1s2[dd]);
                    oc[sp0 + dd * HW] = az * top + wz * bot + f1c;
                }
            }
        }

        // stage next channel into the (single) slab between barriers
        if (c < 2) {
            __syncthreads();                       // all waves done reading
            stage(f2b + (size_t)(c + 1) * SP);
            __syncthreads();                       // slab (c+1) ready
        }
    }
}

extern "C" void kernel_launch(void* const* d_in, const int* in_sizes, int n_in,
                              void* d_out, int out_size, void* d_ws, size_t ws_size,
                              hipStream_t stream) {
    const float* f1  = (const float*)d_in[0];
    const float* f2  = (const float*)d_in[1];
    // d_in[2] = sample_grid (identity meshgrid) — unused by construction
    const float* rfp = (const float*)d_in[3];
    float* out = (float*)d_out;

    comp_xform_px64<<<NB, 256, 0, stream>>>(f1, f2, rfp, out);
}